// Round 8
// baseline (271.289 us; speedup 1.0000x reference)
//
#include <hip/hip_runtime.h>
#include <math.h>

#define BB 16
#define CC 128
#define HH 128
#define WW 128
#define LL 4096

typedef short short8 __attribute__((ext_vector_type(8)));
typedef float f32x4 __attribute__((ext_vector_type(4)));

__device__ __forceinline__ ushort f2bf(float f) {
    union { float f; unsigned u; } un; un.f = f;
    unsigned u = un.u;
    u += 0x7fffu + ((u >> 16) & 1u);   // RNE
    return (ushort)(u >> 16);
}
__device__ __forceinline__ float bf2f(ushort h) {
    union { unsigned u; float f; } un; un.u = ((unsigned)h) << 16;
    return un.f;
}
__device__ __forceinline__ float fast_gelu(float xv) {
    float x2 = xv*xv;
    float arg = xv*(-2.3022100f - 0.1029436f*x2);
    float e = exp2f(arg);
    return xv*__builtin_amdgcn_rcpf(1.f + e);
}

// ---- prep: Wq/Wk -> bf16; cvec = proj@bv + proj_b ----
__global__ __launch_bounds__(256) void prep_small(
    const float* __restrict__ qkv_w, const float* __restrict__ qkv_b,
    const float* __restrict__ proj_w, const float* __restrict__ proj_b,
    ushort* __restrict__ wqk, float* __restrict__ cvec)
{
    int t = threadIdx.x;
    int gid = blockIdx.x*256 + t;
    wqk[gid] = f2bf(qkv_w[gid]);
    if (blockIdx.x == 1 && t < CC) {
        float s = proj_b[t];
        const float* pr = proj_w + t*CC;
        const float* bv = qkv_b + 2*CC;
        for (int c = 0; c < CC; ++c) s += pr[c]*bv[c];
        cvec[t] = s;
    }
}

// ---- guide = dwconv7x7_s2(gelu(bn(x))), bf16 out [b][c][64*64] (unchanged R6) ----
__global__ __launch_bounds__(256) void guide_kernel(
    const float* __restrict__ x, const float* __restrict__ gamma,
    const float* __restrict__ beta, const float* __restrict__ mean,
    const float* __restrict__ var, const float* __restrict__ dww,
    const float* __restrict__ dwb, ushort* __restrict__ gw)
{
    int bc = blockIdx.x;
    int b = bc >> 7, c = bc & 127;
    int ty = blockIdx.y;
    __shared__ __align__(16) float g[69*144];
    int t = threadIdx.x;
    float wreg[49];
    #pragma unroll
    for (int k = 0; k < 49; ++k) wreg[k] = dww[c*49 + k];
    float bias = dwb[c];
    float scl = gamma[c] * rsqrtf(var[c] + 1e-5f);
    float sft = beta[c] - mean[c]*scl;
    const float* xb = x + (size_t)(b*CC + c)*HH*WW;
    int ihbase = 64*ty - 3;
    #pragma unroll
    for (int k = 0; k < 9; ++k) {
        int idx = k*256 + t;
        if (idx < 69*32) {
            int row = idx >> 5, ch = idx & 31;
            int ih = ihbase + row;
            float4 v4 = {0.f, 0.f, 0.f, 0.f};
            if ((unsigned)ih < 128u) {
                float4 xv = *(const float4*)(xb + ih*WW + 4*ch);
                v4.x = fast_gelu(xv.x*scl + sft);
                v4.y = fast_gelu(xv.y*scl + sft);
                v4.z = fast_gelu(xv.z*scl + sft);
                v4.w = fast_gelu(xv.w*scl + sft);
            }
            int f = (row >> 2) & 3;
            *(float4*)(g + row*144 + 4*((ch + 1) ^ f)) = v4;
        }
    }
    if (t < 138) {
        int row = t >> 1;
        int lc = (t & 1) ? 33 : 0;
        int f = (row >> 2) & 3;
        float4 z4 = {0.f, 0.f, 0.f, 0.f};
        *(float4*)(g + row*144 + 4*(lc ^ f)) = z4;
    }
    __syncthreads();
    int vg = t >> 4, owg = t & 15;
    float acc[2][4];
    #pragma unroll
    for (int v = 0; v < 2; ++v)
        #pragma unroll
        for (int hh = 0; hh < 4; ++hh) acc[v][hh] = bias;
    #pragma unroll
    for (int j = 0; j < 9; ++j) {
        int rr = 4*vg + j;
        int f = (rr >> 2) & 3;
        const float* grow = g + rr*144;
        float win[16];
        #pragma unroll
        for (int i = 0; i < 4; ++i) {
            float4 w4 = *(const float4*)(grow + 4*(((2*owg + i) ^ f)));
            win[4*i+0] = w4.x; win[4*i+1] = w4.y;
            win[4*i+2] = w4.z; win[4*i+3] = w4.w;
        }
        #pragma unroll
        for (int v = 0; v < 2; ++v) {
            int kh = j - 2*v;
            if (kh >= 0 && kh <= 6) {
                #pragma unroll
                for (int hh = 0; hh < 4; ++hh)
                    #pragma unroll
                    for (int kw = 0; kw < 7; ++kw)
                        acc[v][hh] += wreg[kh*7 + kw] * win[2*hh + kw + 1];
            }
        }
    }
    int orbase = 32*ty + 2*vg;
    ushort* gdst = gw + ((size_t)(b*CC + c) << 12);
    #pragma unroll
    for (int v = 0; v < 2; ++v) {
        uint2 pk;
        pk.x = (unsigned)f2bf(acc[v][0]) | ((unsigned)f2bf(acc[v][1]) << 16);
        pk.y = (unsigned)f2bf(acc[v][2]) | ((unsigned)f2bf(acc[v][3]) << 16);
        *(uint2*)(gdst + (orbase + v)*64 + 4*owg) = pk;
    }
}

// ==== shared staging: build swizzled bf16 token tile for one 32-l chunk ====
// tok[m][lp][idx], idx = c ^ ((lp&7)<<3)  (ushort units; 16B-chunk XOR swizzle)
// xt: f32 staging tile [32 c][132]
__device__ __forceinline__ void stage_chunk(
    ushort* __restrict__ tok, float* __restrict__ xt,
    const float* __restrict__ x, const ushort* __restrict__ gw,
    int b, int h, int whalf, int t)
{
    // m0 (guide): coalesced uint4 loads + swizzled u16 writes
    {
        int c = t >> 1, r = t & 1;
        const ushort* gsrc = gw + ((size_t)(b*CC + c) << 12) + h*64 + whalf*32 + r*16;
        uint4 g0 = *(const uint4*)gsrc;
        uint4 g1 = *(const uint4*)(gsrc + 8);
        unsigned wd[8] = {g0.x,g0.y,g0.z,g0.w,g1.x,g1.y,g1.z,g1.w};
        #pragma unroll
        for (int k2 = 0; k2 < 8; ++k2) {
            int lp0 = r*16 + 2*k2, lp1 = lp0 + 1;
            tok[lp0*128 + (c ^ ((lp0 & 7) << 3))] = (ushort)wd[k2];
            tok[lp1*128 + (c ^ ((lp1 & 7) << 3))] = (ushort)(wd[k2] >> 16);
        }
    }
    // m1..4: 4 slabs of 32 c through xt
    int cp = t & 15, lgrp = t >> 4;
    for (int slab = 0; slab < 4; ++slab) {
        int c0 = slab*32;
        __syncthreads();   // protect xt reuse
        #pragma unroll
        for (int i = 0; i < 4; ++i) {
            int fc = i*256 + t;
            int cc = fc >> 5, f4 = fc & 31;      // f4: r = f4>>4, wq = f4&15
            int r = f4 >> 4, wq = f4 & 15;
            float4 v = *(const float4*)(x + ((size_t)(b*CC + c0 + cc)*HH + 2*h + r)*WW
                                          + whalf*64 + 4*wq);
            *(float4*)(xt + cc*132 + f4*4) = v;  // col = r*64 + 4wq
        }
        __syncthreads();
        #pragma unroll
        for (int sub = 0; sub < 2; ++sub) {
            int lp = lgrp*2 + sub;
            int key8 = (lp & 7) << 3;
            int slot = ((c0 + 2*cp) ^ key8) >> 1;    // u32 slot within row
            #pragma unroll
            for (int r = 0; r < 2; ++r) {
                float2 lo = *(const float2*)(xt + (2*cp    )*132 + r*64 + 2*lp);
                float2 hi = *(const float2*)(xt + (2*cp + 1)*132 + r*64 + 2*lp);
                unsigned w0 = (unsigned)f2bf(lo.x) | ((unsigned)f2bf(hi.x) << 16); // m=1+2r
                unsigned w1 = (unsigned)f2bf(lo.y) | ((unsigned)f2bf(hi.y) << 16); // m=2+2r
                ((unsigned*)(tok + (1 + 2*r)*4096 + lp*128))[slot] = w0;
                ((unsigned*)(tok + (2 + 2*r)*4096 + lp*128))[slot] = w1;
            }
        }
    }
    __syncthreads();
}

// ---- phase A: per-block partial S (640) + token-sum partial T (640) ----
__global__ __launch_bounds__(256) void s_kernel(
    const float* __restrict__ x, const ushort* __restrict__ gw,
    const ushort* __restrict__ wqk, float* __restrict__ Spart)
{
    __shared__ __align__(16) ushort tok[5*32*128];
    __shared__ __align__(16) float xt[32*132];
    __shared__ float Sred[640];
    int t = threadIdx.x;
    int blk = blockIdx.x;
    int b = blk >> 7, chunk = blk & 127;
    int h = chunk >> 1, whalf = chunk & 1;
    int lane = t & 63, wave = t >> 6;
    int strip = wave*32;
    int l15 = lane & 15, kg = lane >> 4;
    int swz = (l15 & 7) << 3;
    short8 aq[2][4], ak[2][4];
    #pragma unroll
    for (int mt = 0; mt < 2; ++mt)
        #pragma unroll
        for (int kt = 0; kt < 4; ++kt) {
            int off = (strip + mt*16 + l15)*CC + kt*32 + kg*8;
            aq[mt][kt] = *(const short8*)(wqk + off);
            ak[mt][kt] = *(const short8*)(wqk + CC*CC + off);
        }
    stage_chunk(tok, xt, x, gw, b, h, whalf, t);
    // token sums (bias terms) — independent swizzled u16 reads
    float tacc[3] = {0.f, 0.f, 0.f};
    #pragma unroll
    for (int j = 0; j < 3; ++j) {
        int i = t + j*256;
        if (i < 640) {
            int m = i >> 7, cch = i & 127;
            float s = 0.f;
            for (int l = 0; l < 32; ++l)
                s += bf2f(tok[m*4096 + l*128 + (cch ^ ((l & 7) << 3))]);
            tacc[j] = s;
        }
    }
    // MFMA: q0 (m=0), then k per m
    f32x4 q0[2][2] = {};
    #pragma unroll
    for (int kt = 0; kt < 4; ++kt) {
        int ko = (kt*32 + kg*8) ^ swz;
        #pragma unroll
        for (int nt = 0; nt < 2; ++nt) {
            short8 bf = *(const short8*)(tok + (nt*16 + l15)*128 + ko);
            #pragma unroll
            for (int mt = 0; mt < 2; ++mt)
                q0[mt][nt] = __builtin_amdgcn_mfma_f32_16x16x32_bf16(aq[mt][kt], bf, q0[mt][nt], 0, 0, 0);
        }
    }
    float sacc[5][8];
    #pragma unroll
    for (int m = 0; m < 5; ++m) {
        f32x4 ka[2][2] = {};
        #pragma unroll
        for (int kt = 0; kt < 4; ++kt) {
            int ko = (kt*32 + kg*8) ^ swz;
            #pragma unroll
            for (int nt = 0; nt < 2; ++nt) {
                short8 bf = *(const short8*)(tok + m*4096 + (nt*16 + l15)*128 + ko);
                #pragma unroll
                for (int mt = 0; mt < 2; ++mt)
                    ka[mt][nt] = __builtin_amdgcn_mfma_f32_16x16x32_bf16(ak[mt][kt], bf, ka[mt][nt], 0, 0, 0);
            }
        }
        #pragma unroll
        for (int i = 0; i < 8; ++i) sacc[m][i] = 0.f;
        #pragma unroll
        for (int mt = 0; mt < 2; ++mt)
            #pragma unroll
            for (int nt = 0; nt < 2; ++nt)
                #pragma unroll
                for (int rr = 0; rr < 4; ++rr)
                    sacc[m][mt*4 + rr] += q0[mt][nt][rr]*ka[mt][nt][rr];
    }
    #pragma unroll
    for (int m = 0; m < 5; ++m)
        #pragma unroll
        for (int i = 0; i < 8; ++i) {
            float v = sacc[m][i];
            v += __shfl_xor(v, 1); v += __shfl_xor(v, 2);
            v += __shfl_xor(v, 4); v += __shfl_xor(v, 8);
            if (l15 == 0)
                Sred[(strip + (i >> 2)*16 + kg*4 + (i & 3))*5 + m] = v;
        }
    __syncthreads();
    float* Sp = Spart + (size_t)blk*1280;
    for (int i = t; i < 640; i += 256) Sp[i] = Sred[i];
    #pragma unroll
    for (int j = 0; j < 3; ++j) {
        int i = t + j*256;
        if (i < 640) Sp[640 + i] = tacc[j];
    }
}

// ---- reduce partials + exact bias + softmax ----
__global__ __launch_bounds__(256) void softmax_attn(
    const float* __restrict__ Spart,
    const float* __restrict__ qkv_w, const float* __restrict__ qkv_b,
    float* __restrict__ attn)
{
    __shared__ float TsumL[640];   // [m][c]
    __shared__ float SL[640];      // [c][m]
    int b = blockIdx.x, t = threadIdx.x;
    for (int i = t; i < 640; i += 256) {
        float s2 = 0.f, ts = 0.f;
        for (int p = 0; p < 128; ++p) {
            const float* row = Spart + (size_t)(b*128 + p)*1280;
            s2 += row[i];
            ts += row[640 + i];
        }
        SL[i] = s2;
        TsumL[i] = ts;
    }
    __syncthreads();
    if (t < CC) {
        int c = t;
        float bq = qkv_b[c], bk = qkv_b[CC + c];
        const float* wqr = qkv_w + c*CC;
        const float* wkr = qkv_w + (CC + c)*CC;
        float t0dot = 0.f;
        for (int j = 0; j < CC; ++j) t0dot += wqr[j]*TsumL[j];
        float s[5];
        #pragma unroll
        for (int m = 0; m < 5; ++m) {
            float km = 0.f;
            for (int j = 0; j < CC; ++j) km += wkr[j]*TsumL[m*128 + j];
            s[m] = SL[c*5 + m] + bq*km + bk*t0dot + (float)LL*bq*bk;
        }
        const float scale = 0.08838834764831845f;  // 1/sqrt(128)
        float mx = s[0]*scale;
        #pragma unroll
        for (int m = 1; m < 5; ++m) mx = fmaxf(mx, s[m]*scale);
        float e[5], tot = 0.f;
        #pragma unroll
        for (int m = 0; m < 5; ++m) { e[m] = expf(s[m]*scale - mx); tot += e[m]; }
        float inv = 1.f/tot;
        #pragma unroll
        for (int m = 0; m < 5; ++m) attn[(b*CC + c)*5 + m] = e[m]*inv;
    }
}

// ---- PW_m[b] = (proj .* attn_m) @ Wv, bf16 [b][m][c_out][c_in] ----
__global__ __launch_bounds__(256) void pw_kernel(
    const float* __restrict__ qkv_w, const float* __restrict__ proj_w,
    const float* __restrict__ attn, ushort* __restrict__ PW)
{
    __shared__ float attns[CC];
    __shared__ float wvs[32*CC];
    int blk = blockIdx.x;
    int b = blk / 5, m = blk % 5;
    int t = threadIdx.x;
    if (t < CC) attns[t] = attn[(b*CC + t)*5 + m];
    int d = t >> 1, cb = (t & 1)*64;
    float acc[64];
    #pragma unroll
    for (int j = 0; j < 64; ++j) acc[j] = 0.f;
    for (int cc0 = 0; cc0 < CC; cc0 += 32) {
        __syncthreads();
        for (int idx = t; idx < 32*CC; idx += 256) {
            int row = idx >> 7, col = idx & 127;
            wvs[idx] = qkv_w[(2*CC + cc0 + row)*CC + col];
        }
        __syncthreads();
        for (int cl = 0; cl < 32; ++cl) {
            int c = cc0 + cl;
            float a = proj_w[d*CC + c]*attns[c];
            const float* wr = wvs + cl*CC + cb;
            #pragma unroll
            for (int j = 0; j < 64; ++j) acc[j] += a*wr[j];
        }
    }
    ushort* dst = PW + ((size_t)(b*5 + m) << 14) + d*CC + cb;
    #pragma unroll
    for (int j = 0; j < 64; ++j) dst[j] = f2bf(acc[j]);
}

// ---- phase B: Y[l][c_out] = sum_{m,c} tok[m][l][c] * PW_m[c_out][c] + cvec ----
__global__ __launch_bounds__(256) void y_kernel(
    const float* __restrict__ x, const ushort* __restrict__ gw,
    const ushort* __restrict__ PW, const float* __restrict__ cvec,
    float* __restrict__ out)
{
    __shared__ __align__(16) ushort tok[5*32*128];   // reused as ylds[128][36] f32
    __shared__ __align__(16) float xt[32*132];
    int t = threadIdx.x;
    int blk = blockIdx.x;
    int b = blk >> 7, chunk = blk & 127;
    int h = chunk >> 1, whalf = chunk & 1;
    int lane = t & 63, wave = t >> 6;
    int l15 = lane & 15, kg = lane >> 4;
    int swz = (l15 & 7) << 3;
    stage_chunk(tok, xt, x, gw, b, h, whalf, t);
    f32x4 acc[2][2] = {};
    #pragma unroll
    for (int m = 0; m < 5; ++m) {
        const ushort* pwb = PW + ((size_t)(b*5 + m) << 14)
                          + ((wave*32 + l15) << 7) + (kg << 3);
        #pragma unroll
        for (int kt = 0; kt < 4; ++kt) {
            int ko = (kt*32 + kg*8) ^ swz;
            short8 a0 = *(const short8*)(tok + m*4096 + (l15     )*128 + ko);
            short8 a1 = *(const short8*)(tok + m*4096 + (16 + l15)*128 + ko);
            short8 b0 = *(const short8*)(pwb + kt*32);
            short8 b1 = *(const short8*)(pwb + (16 << 7) + kt*32);
            acc[0][0] = __builtin_amdgcn_mfma_f32_16x16x32_bf16(a0, b0, acc[0][0], 0, 0, 0);
            acc[0][1] = __builtin_amdgcn_mfma_f32_16x16x32_bf16(a0, b1, acc[0][1], 0, 0, 0);
            acc[1][0] = __builtin_amdgcn_mfma_f32_16x16x32_bf16(a1, b0, acc[1][0], 0, 0, 0);
            acc[1][1] = __builtin_amdgcn_mfma_f32_16x16x32_bf16(a1, b1, acc[1][1], 0, 0, 0);
        }
    }
    __syncthreads();
    float* ylds = (float*)tok;   // [128][36]
    #pragma unroll
    for (int mt = 0; mt < 2; ++mt)
        #pragma unroll
        for (int ntl = 0; ntl < 2; ++ntl) {
            int cc = wave*32 + ntl*16 + l15;
            float cv = cvec[cc];
            #pragma unroll
            for (int rr = 0; rr < 4; ++rr) {
                int l = mt*16 + kg*4 + rr;
                ylds[cc*36 + l] = acc[mt][ntl][rr] + cv;
            }
        }
    __syncthreads();
    int c = t >> 1, half = t & 1;
    float* ob = out + ((size_t)(b*CC + c) << 12) + h*64 + whalf*32 + half*16;
    const float* yr = ylds + c*36 + half*16;
    #pragma unroll
    for (int j = 0; j < 4; ++j)
        ((float4*)ob)[j] = ((const float4*)yr)[j];
}

extern "C" void kernel_launch(void* const* d_in, const int* in_sizes, int n_in,
                              void* d_out, int out_size, void* d_ws, size_t ws_size,
                              hipStream_t stream) {
    const float* x        = (const float*)d_in[0];
    const float* bn_gamma = (const float*)d_in[1];
    const float* bn_beta  = (const float*)d_in[2];
    const float* bn_mean  = (const float*)d_in[3];
    const float* bn_var   = (const float*)d_in[4];
    const float* dw_w     = (const float*)d_in[5];
    const float* dw_b     = (const float*)d_in[6];
    const float* qkv_w    = (const float*)d_in[7];
    const float* qkv_b    = (const float*)d_in[8];
    const float* proj_w   = (const float*)d_in[9];
    const float* proj_b   = (const float*)d_in[10];
    float* out = (float*)d_out;

    char* w = (char*)d_ws;
    ushort* gw    = (ushort*)w; w += (size_t)BB*CC*LL*2;        // 16.8 MB
    ushort* wqk   = (ushort*)w; w += (size_t)2*CC*CC*2;         // 64 KB
    ushort* PW    = (ushort*)w; w += (size_t)BB*5*CC*CC*2;      // 2.6 MB
    float*  Spart = (float*)w;  w += (size_t)2048*1280*4;       // 10.5 MB
    float*  attn  = (float*)w;  w += (size_t)BB*CC*5*4;         // 40 KB
    float*  cvec  = (float*)w;  w += (size_t)CC*4;

    prep_small<<<128, 256, 0, stream>>>(qkv_w, qkv_b, proj_w, proj_b, wqk, cvec);
    guide_kernel<<<dim3(BB*CC, 2), 256, 0, stream>>>(
        x, bn_gamma, bn_beta, bn_mean, bn_var, dw_w, dw_b, gw);
    s_kernel<<<2048, 256, 0, stream>>>(x, gw, wqk, Spart);
    softmax_attn<<<BB, 256, 0, stream>>>(Spart, qkv_w, qkv_b, attn);
    pw_kernel<<<BB*5, 256, 0, stream>>>(qkv_w, proj_w, attn, PW);
    y_kernel<<<2048, 256, 0, stream>>>(x, gw, PW, cvec, out);
}

// Round 9
// 240.050 us; speedup vs baseline: 1.1301x; 1.1301x over previous
//
#include <hip/hip_runtime.h>
#include <math.h>

#define BB 16
#define CC 128
#define HH 128
#define WW 128
#define LL 4096

typedef short short8 __attribute__((ext_vector_type(8)));
typedef float f32x4 __attribute__((ext_vector_type(4)));

__device__ __forceinline__ ushort f2bf(float f) {
    union { float f; unsigned u; } un; un.f = f;
    unsigned u = un.u;
    u += 0x7fffu + ((u >> 16) & 1u);   // RNE
    return (ushort)(u >> 16);
}
__device__ __forceinline__ float bf2f(ushort h) {
    union { unsigned u; float f; } un; un.u = ((unsigned)h) << 16;
    return un.f;
}
__device__ __forceinline__ float fast_gelu(float xv) {
    float x2 = xv*xv;
    float arg = xv*(-2.3022100f - 0.1029436f*x2);
    float e = exp2f(arg);
    return xv*__builtin_amdgcn_rcpf(1.f + e);
}
__device__ __forceinline__ int swzkey(int r) { return (r & 3) ^ ((r >> 2) & 3); }

// ---- prep: cvec = proj@bv + proj_b ----
__global__ __launch_bounds__(128) void prep_cvec(
    const float* __restrict__ qkv_b, const float* __restrict__ proj_w,
    const float* __restrict__ proj_b, float* __restrict__ cvec)
{
    int t = threadIdx.x;
    float s = proj_b[t];
    const float* pr = proj_w + t*CC;
    const float* bv = qkv_b + 2*CC;
    for (int c = 0; c < CC; ++c) s += pr[c]*bv[c];
    cvec[t] = s;
}

// ---- guide = dwconv7x7_s2(gelu(bn(x))), bf16 out; + fused token-sum partials ----
__global__ __launch_bounds__(256) void guide_kernel(
    const float* __restrict__ x, const float* __restrict__ gamma,
    const float* __restrict__ beta, const float* __restrict__ mean,
    const float* __restrict__ var, const float* __restrict__ dww,
    const float* __restrict__ dwb, ushort* __restrict__ gw,
    float* __restrict__ Tpart)
{
    int bc = blockIdx.x;
    int b = bc >> 7, c = bc & 127;
    int ty = blockIdx.y;
    __shared__ __align__(16) float g[69*144];
    __shared__ float red[5][4];
    int t = threadIdx.x;
    int lane = t & 63, wave = t >> 6;
    float wreg[49];
    #pragma unroll
    for (int k = 0; k < 49; ++k) wreg[k] = dww[c*49 + k];
    float bias = dwb[c];
    float scl = gamma[c] * rsqrtf(var[c] + 1e-5f);
    float sft = beta[c] - mean[c]*scl;
    const float* xb = x + (size_t)(b*CC + c)*HH*WW;
    int ihbase = 64*ty - 3;
    float a00=0.f, a01=0.f, a10=0.f, a11=0.f;
    #pragma unroll
    for (int k = 0; k < 9; ++k) {
        int idx = k*256 + t;
        if (idx < 69*32) {
            int row = idx >> 5, ch = idx & 31;
            int ih = ihbase + row;
            float4 v4 = {0.f, 0.f, 0.f, 0.f};
            if ((unsigned)ih < 128u) {
                float4 xv = *(const float4*)(xb + ih*WW + 4*ch);
                if (row >= 3 && row < 67) {   // core: exact partition across ty
                    float e0 = xv.x + xv.z, e1 = xv.y + xv.w;
                    if (ih & 1) { a10 += e0; a11 += e1; }
                    else        { a00 += e0; a01 += e1; }
                }
                v4.x = fast_gelu(xv.x*scl + sft);
                v4.y = fast_gelu(xv.y*scl + sft);
                v4.z = fast_gelu(xv.z*scl + sft);
                v4.w = fast_gelu(xv.w*scl + sft);
            }
            int f = (row >> 2) & 3;
            *(float4*)(g + row*144 + 4*((ch + 1) ^ f)) = v4;
        }
    }
    if (t < 138) {
        int row = t >> 1;
        int lc = (t & 1) ? 33 : 0;
        int f = (row >> 2) & 3;
        float4 z4 = {0.f, 0.f, 0.f, 0.f};
        *(float4*)(g + row*144 + 4*(lc ^ f)) = z4;
    }
    __syncthreads();
    int vg = t >> 4, owg = t & 15;
    float acc[2][4];
    #pragma unroll
    for (int v = 0; v < 2; ++v)
        #pragma unroll
        for (int hh = 0; hh < 4; ++hh) acc[v][hh] = bias;
    #pragma unroll
    for (int j = 0; j < 9; ++j) {
        int rr = 4*vg + j;
        int f = (rr >> 2) & 3;
        const float* grow = g + rr*144;
        float win[16];
        #pragma unroll
        for (int i = 0; i < 4; ++i) {
            float4 w4 = *(const float4*)(grow + 4*(((2*owg + i) ^ f)));
            win[4*i+0] = w4.x; win[4*i+1] = w4.y;
            win[4*i+2] = w4.z; win[4*i+3] = w4.w;
        }
        #pragma unroll
        for (int v = 0; v < 2; ++v) {
            int kh = j - 2*v;
            if (kh >= 0 && kh <= 6) {
                #pragma unroll
                for (int hh = 0; hh < 4; ++hh)
                    #pragma unroll
                    for (int kw = 0; kw < 7; ++kw)
                        acc[v][hh] += wreg[kh*7 + kw] * win[2*hh + kw + 1];
            }
        }
    }
    int orbase = 32*ty + 2*vg;
    ushort* gdst = gw + ((size_t)(b*CC + c) << 12);
    float gsum = 0.f;
    #pragma unroll
    for (int v = 0; v < 2; ++v) {
        uint2 pk;
        pk.x = (unsigned)f2bf(acc[v][0]) | ((unsigned)f2bf(acc[v][1]) << 16);
        pk.y = (unsigned)f2bf(acc[v][2]) | ((unsigned)f2bf(acc[v][3]) << 16);
        *(uint2*)(gdst + (orbase + v)*64 + 4*owg) = pk;
        gsum += acc[v][0] + acc[v][1] + acc[v][2] + acc[v][3];
    }
    float vals[5] = {gsum, a00, a01, a10, a11};
    #pragma unroll
    for (int v = 0; v < 5; ++v) {
        float s = vals[v];
        s += __shfl_xor(s, 1);  s += __shfl_xor(s, 2);
        s += __shfl_xor(s, 4);  s += __shfl_xor(s, 8);
        s += __shfl_xor(s, 16); s += __shfl_xor(s, 32);
        if (lane == 0) red[v][wave] = s;
    }
    __syncthreads();
    if (t < 5)
        Tpart[((size_t)(b*2 + ty)*5 + t)*128 + c] =
            red[t][0] + red[t][1] + red[t][2] + red[t][3];
}

// ---- Gram_m[i,j] = sum_l t0[i,l] * t_m[j,l]   (l-contraction, natural layout) ----
// grid 256 = b(16) x kq(8) x grp(2); 512 threads; K=512 l per block, 16 steps.
// grp0: B planes {m0,m1,m2} (x row 2h); grp1: {m0(A only),m3,m4} (x row 2h+1).
__global__ __launch_bounds__(512) void gram_kernel(
    const float* __restrict__ x, const ushort* __restrict__ gw,
    float* __restrict__ Gpart)
{
    __shared__ __align__(16) ushort tokb[2*3*128*32];   // 48 KB dbuf
    int t = threadIdx.x;
    int blk = blockIdx.x;
    int b = blk >> 4, kq = (blk >> 1) & 7, grp = blk & 1;
    int lane = t & 63, wid = t >> 6;
    int l15 = lane & 15, kg = lane >> 4;
    int js = t >> 2, sub = t & 3;
    int keyj = swzkey(js);
    const float* xrow0 = x + ((size_t)(b*CC + js)*HH + grp)*WW;
    const ushort* gwrow = gw + ((size_t)(b*CC + js) << 12);
    f32x4 acc[8][3];
    #pragma unroll
    for (int i = 0; i < 8; ++i)
        #pragma unroll
        for (int q = 0; q < 3; ++q) acc[i][q] = (f32x4){0.f,0.f,0.f,0.f};
    int H0 = kq*8;
    float4 xa, xbv, xc, xd;
    uint4 gr;
    {
        const float* xp = xrow0 + (2*H0)*WW + sub*16;
        xa = *(const float4*)(xp);
        xbv = *(const float4*)(xp + 4);
        xc = *(const float4*)(xp + 8);
        xd = *(const float4*)(xp + 12);
        gr = *(const uint4*)(gwrow + H0*64 + sub*8);
    }
    for (int s = 0; s < 16; ++s) {
        int cur = s & 1;
        ushort* tb = tokb + cur*(3*128*32);
        // de-interleave + swizzled b128 writes (3 per thread)
        {
            unsigned lo0 = (unsigned)f2bf(xa.x) | ((unsigned)f2bf(xa.z) << 16);
            unsigned lo1 = (unsigned)f2bf(xbv.x) | ((unsigned)f2bf(xbv.z) << 16);
            unsigned lo2 = (unsigned)f2bf(xc.x) | ((unsigned)f2bf(xc.z) << 16);
            unsigned lo3 = (unsigned)f2bf(xd.x) | ((unsigned)f2bf(xd.z) << 16);
            unsigned hi0 = (unsigned)f2bf(xa.y) | ((unsigned)f2bf(xa.w) << 16);
            unsigned hi1 = (unsigned)f2bf(xbv.y) | ((unsigned)f2bf(xbv.w) << 16);
            unsigned hi2 = (unsigned)f2bf(xc.y) | ((unsigned)f2bf(xc.w) << 16);
            unsigned hi3 = (unsigned)f2bf(xd.y) | ((unsigned)f2bf(xd.w) << 16);
            uint4 lov = {lo0, lo1, lo2, lo3};
            uint4 hiv = {hi0, hi1, hi2, hi3};
            int chs = (sub ^ keyj) << 3;
            *(uint4*)(tb + (1*128 + js)*32 + chs) = lov;
            *(uint4*)(tb + (2*128 + js)*32 + chs) = hiv;
            *(uint4*)(tb + (0*128 + js)*32 + chs) = gr;
        }
        if (s < 15) {
            int sn = s + 1;
            int h = H0 + (sn >> 1), whalf = sn & 1;
            const float* xp = xrow0 + (2*h)*WW + whalf*64 + sub*16;
            xa = *(const float4*)(xp);
            xbv = *(const float4*)(xp + 4);
            xc = *(const float4*)(xp + 8);
            xd = *(const float4*)(xp + 12);
            gr = *(const uint4*)(gwrow + h*64 + whalf*32 + sub*8);
        }
        __syncthreads();
        const ushort* tb2 = tokb + cur*(3*128*32);
        short8 af[8];
        #pragma unroll
        for (int f = 0; f < 8; ++f) {
            int row = f*16 + l15;
            af[f] = *(const short8*)(tb2 + row*32 + ((kg ^ swzkey(row)) << 3));
        }
        if (grp == 0) {
            #pragma unroll
            for (int q = 0; q < 3; ++q) {
                int nf = wid*3 + q;
                int pl = nf >> 3, jr = (nf & 7)*16 + l15;
                short8 bf = *(const short8*)(tb2 + (pl*128 + jr)*32 + ((kg ^ swzkey(jr)) << 3));
                #pragma unroll
                for (int f = 0; f < 8; ++f)
                    acc[f][q] = __builtin_amdgcn_mfma_f32_16x16x32_bf16(af[f], bf, acc[f][q], 0, 0, 0);
            }
        } else {
            #pragma unroll
            for (int q = 0; q < 2; ++q) {
                int nf = wid*2 + q;
                int pl = 1 + (nf >> 3), jr = (nf & 7)*16 + l15;
                short8 bf = *(const short8*)(tb2 + (pl*128 + jr)*32 + ((kg ^ swzkey(jr)) << 3));
                #pragma unroll
                for (int f = 0; f < 8; ++f)
                    acc[f][q] = __builtin_amdgcn_mfma_f32_16x16x32_bf16(af[f], bf, acc[f][q], 0, 0, 0);
            }
        }
    }
    float* gp = Gpart + (size_t)(b*8 + kq)*81920;
    if (grp == 0) {
        #pragma unroll
        for (int f = 0; f < 8; ++f)
            #pragma unroll
            for (int q = 0; q < 3; ++q) {
                int n = (wid*3 + q)*16 + l15;
                #pragma unroll
                for (int r = 0; r < 4; ++r)
                    gp[(size_t)(f*16 + kg*4 + r)*640 + n] = acc[f][q][r];
            }
    } else {
        #pragma unroll
        for (int f = 0; f < 8; ++f)
            #pragma unroll
            for (int q = 0; q < 2; ++q) {
                int n = 384 + (wid*2 + q)*16 + l15;
                #pragma unroll
                for (int r = 0; r < 4; ++r)
                    gp[(size_t)(f*16 + kg*4 + r)*640 + n] = acc[f][q][r];
            }
    }
}

// ---- S[b,c,m] = Wq[c,:]·Gram_m·Wk[c,:] + exact bias terms (all f32) ----
__global__ __launch_bounds__(256) void combine_kernel(
    const float* __restrict__ Gpart, const float* __restrict__ Tpart,
    const float* __restrict__ qkv_w, const float* __restrict__ qkv_b,
    float* __restrict__ Sout)
{
    __shared__ float Gm[128*129];    // Gram_m, then U = Gm·Wk^T
    __shared__ float Wks[128*129];
    __shared__ float Ts[5*128];
    int blk = blockIdx.x;
    int b = blk / 5, m = blk % 5;
    int t = threadIdx.x;
    for (int idx4 = t; idx4 < 4096; idx4 += 256) {
        int i = idx4 >> 5, j4 = idx4 & 31;
        float4 ws = {0.f,0.f,0.f,0.f};
        #pragma unroll
        for (int kq = 0; kq < 8; ++kq) {
            float4 v = *(const float4*)(Gpart + (size_t)(b*8+kq)*81920
                                        + (size_t)i*640 + m*128 + j4*4);
            ws.x += v.x; ws.y += v.y; ws.z += v.z; ws.w += v.w;
        }
        Gm[i*129 + j4*4 + 0] = ws.x;
        Gm[i*129 + j4*4 + 1] = ws.y;
        Gm[i*129 + j4*4 + 2] = ws.z;
        Gm[i*129 + j4*4 + 3] = ws.w;
        float4 wk = *(const float4*)(qkv_w + (size_t)(128 + i)*128 + j4*4);
        Wks[i*129 + j4*4 + 0] = wk.x;
        Wks[i*129 + j4*4 + 1] = wk.y;
        Wks[i*129 + j4*4 + 2] = wk.z;
        Wks[i*129 + j4*4 + 3] = wk.w;
    }
    for (int i2 = t; i2 < 640; i2 += 256) {
        int v = i2 >> 7, c = i2 & 127;
        Ts[v*128 + c] = Tpart[((size_t)(b*2 + 0)*5 + v)*128 + c]
                      + Tpart[((size_t)(b*2 + 1)*5 + v)*128 + c];
    }
    __syncthreads();
    int ti = t >> 4, tc = t & 15;
    float au[8][8];
    #pragma unroll
    for (int r = 0; r < 8; ++r)
        #pragma unroll
        for (int s2 = 0; s2 < 8; ++s2) au[r][s2] = 0.f;
    for (int j = 0; j < 128; ++j) {
        float gmr[8], wkr[8];
        #pragma unroll
        for (int r = 0; r < 8; ++r) gmr[r] = Gm[(ti*8 + r)*129 + j];
        #pragma unroll
        for (int s2 = 0; s2 < 8; ++s2) wkr[s2] = Wks[(tc*8 + s2)*129 + j];
        #pragma unroll
        for (int r = 0; r < 8; ++r)
            #pragma unroll
            for (int s2 = 0; s2 < 8; ++s2) au[r][s2] += gmr[r]*wkr[s2];
    }
    __syncthreads();
    #pragma unroll
    for (int r = 0; r < 8; ++r)
        #pragma unroll
        for (int s2 = 0; s2 < 8; ++s2)
            Gm[(ti*8 + r)*129 + tc*8 + s2] = au[r][s2];   // U[i][c]
    __syncthreads();
    if (t < 128) {
        int c = t;
        const float4* wq4p = (const float4*)(qkv_w + (size_t)c*128);
        float bq = qkv_b[c], bk = qkv_b[128 + c];
        float ud = 0.f, t0d = 0.f, km = 0.f;
        for (int k4 = 0; k4 < 32; ++k4) {
            float4 w4 = wq4p[k4];
            int k = k4*4;
            ud  += w4.x*Gm[(k+0)*129 + c] + w4.y*Gm[(k+1)*129 + c]
                 + w4.z*Gm[(k+2)*129 + c] + w4.w*Gm[(k+3)*129 + c];
            t0d += w4.x*Ts[k+0] + w4.y*Ts[k+1] + w4.z*Ts[k+2] + w4.w*Ts[k+3];
            km  += Wks[c*129 + k+0]*Ts[m*128 + k+0] + Wks[c*129 + k+1]*Ts[m*128 + k+1]
                 + Wks[c*129 + k+2]*Ts[m*128 + k+2] + Wks[c*129 + k+3]*Ts[m*128 + k+3];
        }
        Sout[(size_t)(b*128 + c)*5 + m] = ud + bq*km + bk*t0d + 4096.0f*bq*bk;
    }
}

// ---- softmax ----
__global__ __launch_bounds__(128) void softmax_attn(
    const float* __restrict__ Sout, float* __restrict__ attn)
{
    int b = blockIdx.x, c = threadIdx.x;
    const float* sp = Sout + (size_t)(b*128 + c)*5;
    const float scale = 0.08838834764831845f;  // 1/sqrt(128)
    float s[5];
    #pragma unroll
    for (int m = 0; m < 5; ++m) s[m] = sp[m]*scale;
    float mx = s[0];
    #pragma unroll
    for (int m = 1; m < 5; ++m) mx = fmaxf(mx, s[m]);
    float e[5], tot = 0.f;
    #pragma unroll
    for (int m = 0; m < 5; ++m) { e[m] = expf(s[m] - mx); tot += e[m]; }
    float inv = 1.f/tot;
    #pragma unroll
    for (int m = 0; m < 5; ++m) attn[(size_t)(b*128 + c)*5 + m] = e[m]*inv;
}

// ---- PW_m[b] = (proj .* attn_m) @ Wv, bf16 ----
__global__ __launch_bounds__(256) void pw_kernel(
    const float* __restrict__ qkv_w, const float* __restrict__ proj_w,
    const float* __restrict__ attn, ushort* __restrict__ PW)
{
    __shared__ float attns[CC];
    __shared__ float wvs[32*CC];
    int blk = blockIdx.x;
    int b = blk / 5, m = blk % 5;
    int t = threadIdx.x;
    if (t < CC) attns[t] = attn[(b*CC + t)*5 + m];
    int d = t >> 1, cb = (t & 1)*64;
    float acc[64];
    #pragma unroll
    for (int j = 0; j < 64; ++j) acc[j] = 0.f;
    for (int cc0 = 0; cc0 < CC; cc0 += 32) {
        __syncthreads();
        for (int idx = t; idx < 32*CC; idx += 256) {
            int row = idx >> 7, col = idx & 127;
            wvs[idx] = qkv_w[(2*CC + cc0 + row)*CC + col];
        }
        __syncthreads();
        for (int cl = 0; cl < 32; ++cl) {
            int c = cc0 + cl;
            float a = proj_w[d*CC + c]*attns[c];
            const float* wr = wvs + cl*CC + cb;
            #pragma unroll
            for (int j = 0; j < 64; ++j) acc[j] += a*wr[j];
        }
    }
    ushort* dst = PW + ((size_t)(b*5 + m) << 14) + d*CC + cb;
    #pragma unroll
    for (int j = 0; j < 64; ++j) dst[j] = f2bf(acc[j]);
}

// ==== stage 5 tokens swizzled [l][c] (unchanged from R8, used by y only) ====
__device__ __forceinline__ void stage_chunk(
    ushort* __restrict__ tok, float* __restrict__ xt,
    const float* __restrict__ x, const ushort* __restrict__ gw,
    int b, int h, int whalf, int t)
{
    {
        int c = t >> 1, r = t & 1;
        const ushort* gsrc = gw + ((size_t)(b*CC + c) << 12) + h*64 + whalf*32 + r*16;
        uint4 g0 = *(const uint4*)gsrc;
        uint4 g1 = *(const uint4*)(gsrc + 8);
        unsigned wd[8] = {g0.x,g0.y,g0.z,g0.w,g1.x,g1.y,g1.z,g1.w};
        #pragma unroll
        for (int k2 = 0; k2 < 8; ++k2) {
            int lp0 = r*16 + 2*k2, lp1 = lp0 + 1;
            tok[lp0*128 + (c ^ ((lp0 & 7) << 3))] = (ushort)wd[k2];
            tok[lp1*128 + (c ^ ((lp1 & 7) << 3))] = (ushort)(wd[k2] >> 16);
        }
    }
    int cp = t & 15, lgrp = t >> 4;
    for (int slab = 0; slab < 4; ++slab) {
        int c0 = slab*32;
        __syncthreads();
        #pragma unroll
        for (int i = 0; i < 4; ++i) {
            int fc = i*256 + t;
            int cc = fc >> 5, f4 = fc & 31;
            int r = f4 >> 4, wq = f4 & 15;
            float4 v = *(const float4*)(x + ((size_t)(b*CC + c0 + cc)*HH + 2*h + r)*WW
                                          + whalf*64 + 4*wq);
            *(float4*)(xt + cc*132 + f4*4) = v;
        }
        __syncthreads();
        #pragma unroll
        for (int sub = 0; sub < 2; ++sub) {
            int lp = lgrp*2 + sub;
            int key8 = (lp & 7) << 3;
            int slot = ((c0 + 2*cp) ^ key8) >> 1;
            #pragma unroll
            for (int r = 0; r < 2; ++r) {
                float2 lo = *(const float2*)(xt + (2*cp    )*132 + r*64 + 2*lp);
                float2 hi = *(const float2*)(xt + (2*cp + 1)*132 + r*64 + 2*lp);
                unsigned w0 = (unsigned)f2bf(lo.x) | ((unsigned)f2bf(hi.x) << 16);
                unsigned w1 = (unsigned)f2bf(lo.y) | ((unsigned)f2bf(hi.y) << 16);
                ((unsigned*)(tok + (1 + 2*r)*4096 + lp*128))[slot] = w0;
                ((unsigned*)(tok + (2 + 2*r)*4096 + lp*128))[slot] = w1;
            }
        }
    }
    __syncthreads();
}

// ---- phase B: Y[l][c_out] = sum_{m,c} tok[m][l][c] * PW_m[c_out][c] + cvec ----
__global__ __launch_bounds__(256) void y_kernel(
    const float* __restrict__ x, const ushort* __restrict__ gw,
    const ushort* __restrict__ PW, const float* __restrict__ cvec,
    float* __restrict__ out)
{
    __shared__ __align__(16) ushort tok[5*32*128];
    __shared__ __align__(16) float xt[32*132];
    int t = threadIdx.x;
    int blk = blockIdx.x;
    int b = blk >> 7, chunk = blk & 127;
    int h = chunk >> 1, whalf = chunk & 1;
    int lane = t & 63, wave = t >> 6;
    int l15 = lane & 15, kg = lane >> 4;
    int swz = (l15 & 7) << 3;
    stage_chunk(tok, xt, x, gw, b, h, whalf, t);
    f32x4 acc[2][2] = {};
    #pragma unroll
    for (int m = 0; m < 5; ++m) {
        const ushort* pwb = PW + ((size_t)(b*5 + m) << 14)
                          + ((wave*32 + l15) << 7) + (kg << 3);
        #pragma unroll
        for (int kt = 0; kt < 4; ++kt) {
            int ko = (kt*32 + kg*8) ^ swz;
            short8 a0 = *(const short8*)(tok + m*4096 + (l15     )*128 + ko);
            short8 a1 = *(const short8*)(tok + m*4096 + (16 + l15)*128 + ko);
            short8 b0 = *(const short8*)(pwb + kt*32);
            short8 b1 = *(const short8*)(pwb + (16 << 7) + kt*32);
            acc[0][0] = __builtin_amdgcn_mfma_f32_16x16x32_bf16(a0, b0, acc[0][0], 0, 0, 0);
            acc[0][1] = __builtin_amdgcn_mfma_f32_16x16x32_bf16(a0, b1, acc[0][1], 0, 0, 0);
            acc[1][0] = __builtin_amdgcn_mfma_f32_16x16x32_bf16(a1, b0, acc[1][0], 0, 0, 0);
            acc[1][1] = __builtin_amdgcn_mfma_f32_16x16x32_bf16(a1, b1, acc[1][1], 0, 0, 0);
        }
    }
    __syncthreads();
    float* ylds = (float*)tok;   // [128][36]
    #pragma unroll
    for (int mt = 0; mt < 2; ++mt)
        #pragma unroll
        for (int ntl = 0; ntl < 2; ++ntl) {
            int cc = wave*32 + ntl*16 + l15;
            float cv = cvec[cc];
            #pragma unroll
            for (int rr = 0; rr < 4; ++rr) {
                int l = mt*16 + kg*4 + rr;
                ylds[cc*36 + l] = acc[mt][ntl][rr] + cv;
            }
        }
    __syncthreads();
    int c = t >> 1, half = t & 1;
    float* ob = out + ((size_t)(b*CC + c) << 12) + h*64 + whalf*32 + half*16;
    const float* yr = ylds + c*36 + half*16;
    #pragma unroll
    for (int j = 0; j < 4; ++j)
        ((float4*)ob)[j] = ((const float4*)yr)[j];
}

extern "C" void kernel_launch(void* const* d_in, const int* in_sizes, int n_in,
                              void* d_out, int out_size, void* d_ws, size_t ws_size,
                              hipStream_t stream) {
    const float* x        = (const float*)d_in[0];
    const float* bn_gamma = (const float*)d_in[1];
    const float* bn_beta  = (const float*)d_in[2];
    const float* bn_mean  = (const float*)d_in[3];
    const float* bn_var   = (const float*)d_in[4];
    const float* dw_w     = (const float*)d_in[5];
    const float* dw_b     = (const float*)d_in[6];
    const float* qkv_w    = (const float*)d_in[7];
    const float* qkv_b    = (const float*)d_in[8];
    const float* proj_w   = (const float*)d_in[9];
    const float* proj_b   = (const float*)d_in[10];
    float* out = (float*)d_out;

    char* w = (char*)d_ws;
    ushort* gw    = (ushort*)w; w += (size_t)BB*CC*LL*2;          // 16.8 MB
    ushort* PW    = (ushort*)w; w += (size_t)BB*5*CC*CC*2;        // 2.6 MB
    float*  Gpart = (float*)w;  w += (size_t)16*8*128*640*4;      // 41.9 MB
    float*  Tpart = (float*)w;  w += (size_t)BB*2*5*128*4;        // 82 KB
    float*  Sout  = (float*)w;  w += (size_t)BB*CC*5*4;           // 40 KB
    float*  attn  = (float*)w;  w += (size_t)BB*CC*5*4;           // 40 KB
    float*  cvec  = (float*)w;  w += (size_t)CC*4;

    prep_cvec<<<1, 128, 0, stream>>>(qkv_b, proj_w, proj_b, cvec);
    guide_kernel<<<dim3(BB*CC, 2), 256, 0, stream>>>(
        x, bn_gamma, bn_beta, bn_mean, bn_var, dw_w, dw_b, gw, Tpart);
    gram_kernel<<<256, 512, 0, stream>>>(x, gw, Gpart);
    combine_kernel<<<80, 256, 0, stream>>>(Gpart, Tpart, qkv_w, qkv_b, Sout);
    softmax_attn<<<BB, 128, 0, stream>>>(Sout, attn);
    pw_kernel<<<BB*5, 256, 0, stream>>>(qkv_w, proj_w, attn, PW);
    y_kernel<<<2048, 256, 0, stream>>>(x, gw, PW, cvec, out);
}